// Round 1
// baseline (1716.823 us; speedup 1.0000x reference)
//
#include <hip/hip_runtime.h>
#include <stdint.h>

// Problem constants (fixed by the reference)
#define M_DIM 8192
#define K_DIM 4096
#define N_DIM 11008
// 4-bit nibbles, 8 per int32 word packed along K; group size 128 along K.

typedef __attribute__((ext_vector_type(8))) short bf16x8;   // 8 bf16 = 4 VGPRs (MFMA A/B frag)
typedef __attribute__((ext_vector_type(4))) float f32x4;    // MFMA C/D frag

// round-to-nearest (ties up) fp32 -> bf16, packed pair. Error budget analysis says
// tie-bias is irrelevant here (threshold 0.3375, our error ~0.05 worst-case).
__device__ __forceinline__ uint32_t pack2_bf16(float lo, float hi) {
    uint32_t ulo = (__float_as_uint(lo) + 0x8000u) >> 16;
    uint32_t uhi = (__float_as_uint(hi) + 0x8000u) & 0xFFFF0000u;
    return uhi | ulo;
}

// Unpack one packed int32 (8 nibbles, nibble i = k-offset i) into 8 dequantized
// bf16 values (4 packed regs, ascending k). Magic: 0x43000000|(nib<<16) is the
// fp32 bit pattern of (128+nib); then w = (128+q)*s + b with b = -(128+z)*s.
__device__ __forceinline__ uint4 dequant_word(uint32_t w, float s, float b) {
    const uint32_t MG = 0x43000000u, MK = 0x000F0000u;
    float f0 = __uint_as_float(((w << 16) & MK) | MG);
    float f1 = __uint_as_float(((w << 12) & MK) | MG);
    float f2 = __uint_as_float(((w <<  8) & MK) | MG);
    float f3 = __uint_as_float(((w <<  4) & MK) | MG);
    float f4 = __uint_as_float(( w        & MK) | MG);
    float f5 = __uint_as_float(((w >>  4) & MK) | MG);
    float f6 = __uint_as_float(((w >>  8) & MK) | MG);
    float f7 = __uint_as_float(((w >> 12) & MK) | MG);
    uint4 o;
    o.x = pack2_bf16(fmaf(f0, s, b), fmaf(f1, s, b));
    o.y = pack2_bf16(fmaf(f2, s, b), fmaf(f3, s, b));
    o.z = pack2_bf16(fmaf(f4, s, b), fmaf(f5, s, b));
    o.w = pack2_bf16(fmaf(f6, s, b), fmaf(f7, s, b));
    return o;
}

// Fused 4-bit-dequant bf16-MFMA GEMM.
// Block tile 128(M) x 128(N) x 64(K), 256 threads = 4 waves in 2x2.
// Each wave: 64x64 output = 4x4 grid of 16x16 tiles, mfma_f32_16x16x32_bf16.
// LDS is "fragment order": 1KB blocks per (tile, kstep); within a block lane l's
// 16B chunk = frag[row/col = l&15][k = (l>>4)*8 .. +7]. Compute reads are
// lane-linear ds_read_b128 -> conflict-free.
__global__ __launch_bounds__(256, 2)
void qgemm_fused(const float* __restrict__ x, const int* __restrict__ Wq,
                 const float* __restrict__ scales, const float* __restrict__ zeros,
                 float* __restrict__ out) {
    __shared__ uint32_t As[4096];   // 16 KB: 16 blocks (8 m-tiles x 2 ksteps) of 1KB
    __shared__ uint32_t Bs[4096];   // 16 KB: 16 blocks (8 n-tiles x 2 ksteps) of 1KB

    const int tid  = threadIdx.x;
    const int lane = tid & 63;
    const int wv   = tid >> 6;
    const int wm   = wv >> 1, wn = wv & 1;   // 2x2 wave grid

    const int m0 = blockIdx.x * 128;
    const int n0 = blockIdx.y * 128;

    // ---- B staging coords: thread owns column c (0..127), rows rh*4 .. rh*4+3
    const int bc  = tid & 127;
    const int brh = tid >> 7;

    // ---- A staging coords: 4 slots/thread; slot = (block 0..15, lane-in-block)
    int a_row[4], a_col[4], a_dst[4];
#pragma unroll
    for (int j = 0; j < 4; ++j) {
        int sl  = tid + 256 * j;
        int blk = sl >> 6;          // 0..15 = m-tile*2 + kstep
        int ln  = sl & 63;
        int mt  = blk >> 1, ks = blk & 1;
        a_row[j] = m0 + mt * 16 + (ln & 15);
        a_col[j] = ks * 32 + (ln >> 4) * 8;        // k offset within stage
        a_dst[j] = blk * 256 + ln * 4;             // u32 index into As
    }

    f32x4 acc[4][4];
#pragma unroll
    for (int mt = 0; mt < 4; ++mt)
#pragma unroll
        for (int nt = 0; nt < 4; ++nt)
            acc[mt][nt] = (f32x4){0.f, 0.f, 0.f, 0.f};

    // ---- initial prefetch: stage 0 + group-0 scale/zero
    float4   pa[4][2];
    uint32_t pw[4];
    float    s_raw, z_raw;
#pragma unroll
    for (int j = 0; j < 4; ++j) {
        const float4* p = reinterpret_cast<const float4*>(
            x + (size_t)a_row[j] * K_DIM + a_col[j]);
        pa[j][0] = p[0];
        pa[j][1] = p[1];
    }
#pragma unroll
    for (int j = 0; j < 4; ++j) {
        int r = brh * 4 + j;
        pw[j] = (uint32_t)Wq[(size_t)r * N_DIM + n0 + bc];
    }
    s_raw = scales[n0 + bc];
    z_raw = zeros[n0 + bc];

    float sv = 0.f, bv = 0.f;

    for (int kk = 0; kk < K_DIM; kk += 64) {
        // group (128 k) boundary: fold zero-point into the fma constant
        if ((kk & 127) == 0) {
            sv = s_raw;
            bv = -(128.0f + z_raw) * s_raw;
        }

        // ---- write A tile (fp32 -> bf16) into fragment-order LDS
#pragma unroll
        for (int j = 0; j < 4; ++j) {
            uint4 o;
            o.x = pack2_bf16(pa[j][0].x, pa[j][0].y);
            o.y = pack2_bf16(pa[j][0].z, pa[j][0].w);
            o.z = pack2_bf16(pa[j][1].x, pa[j][1].y);
            o.w = pack2_bf16(pa[j][1].z, pa[j][1].w);
            *reinterpret_cast<uint4*>(&As[a_dst[j]]) = o;
        }
        // ---- dequant + write B tile. One packed word = one 16B B-frag chunk.
#pragma unroll
        for (int j = 0; j < 4; ++j) {
            int r  = brh * 4 + j;            // packed row within stage (k = r*8..)
            uint4 o = dequant_word(pw[j], sv, bv);
            int ks  = r >> 2, q = r & 3;
            int blk = ((bc >> 4) << 1) | ks;
            *reinterpret_cast<uint4*>(&Bs[blk * 256 + (q * 16 + (bc & 15)) * 4]) = o;
        }
        __syncthreads();

        // ---- prefetch next stage (global -> regs), overlapped with compute below
        int kn = kk + 64;
        if (kn < K_DIM) {
#pragma unroll
            for (int j = 0; j < 4; ++j) {
                const float4* p = reinterpret_cast<const float4*>(
                    x + (size_t)a_row[j] * K_DIM + kn + a_col[j]);
                pa[j][0] = p[0];
                pa[j][1] = p[1];
            }
            int kp0 = kn >> 3;
#pragma unroll
            for (int j = 0; j < 4; ++j) {
                int r = brh * 4 + j;
                pw[j] = (uint32_t)Wq[(size_t)(kp0 + r) * N_DIM + n0 + bc];
            }
            if ((kn & 127) == 0) {
                int g = kn >> 7;
                s_raw = scales[(size_t)g * N_DIM + n0 + bc];
                z_raw = zeros[(size_t)g * N_DIM + n0 + bc];
            }
        }

        // ---- compute: 2 ksteps x 16 MFMAs per wave
#pragma unroll
        for (int ks = 0; ks < 2; ++ks) {
            bf16x8 af[4], bfr[4];
#pragma unroll
            for (int mt = 0; mt < 4; ++mt)
                af[mt] = *reinterpret_cast<const bf16x8*>(
                    &As[(((wm * 4 + mt) << 1) | ks) * 256 + lane * 4]);
#pragma unroll
            for (int nt = 0; nt < 4; ++nt)
                bfr[nt] = *reinterpret_cast<const bf16x8*>(
                    &Bs[(((wn * 4 + nt) << 1) | ks) * 256 + lane * 4]);
#pragma unroll
            for (int mt = 0; mt < 4; ++mt)
#pragma unroll
                for (int nt = 0; nt < 4; ++nt)
                    acc[mt][nt] = __builtin_amdgcn_mfma_f32_16x16x32_bf16(
                        af[mt], bfr[nt], acc[mt][nt], 0, 0, 0);
        }
        __syncthreads();
    }

    // ---- epilogue: C/D layout col = lane&15, row = (lane>>4)*4 + reg  [m89/m91]
    const int colc = lane & 15, qr = lane >> 4;
#pragma unroll
    for (int mt = 0; mt < 4; ++mt) {
#pragma unroll
        for (int nt = 0; nt < 4; ++nt) {
            int row0 = m0 + (wm * 4 + mt) * 16 + qr * 4;
            int c    = n0 + (wn * 4 + nt) * 16 + colc;
#pragma unroll
            for (int i = 0; i < 4; ++i)
                out[(size_t)(row0 + i) * N_DIM + c] = acc[mt][nt][i];
        }
    }
}

extern "C" void kernel_launch(void* const* d_in, const int* in_sizes, int n_in,
                              void* d_out, int out_size, void* d_ws, size_t ws_size,
                              hipStream_t stream) {
    const float* x      = (const float*)d_in[0];
    const int*   Wq     = (const int*)d_in[1];
    const float* scales = (const float*)d_in[2];
    const float* zeros  = (const float*)d_in[3];
    float*       out    = (float*)d_out;

    dim3 grid(M_DIM / 128, N_DIM / 128);   // 64 x 86 = 5504 blocks
    qgemm_fused<<<grid, dim3(256), 0, stream>>>(x, Wq, scales, zeros, out);
}

// Round 2
// 1086.871 us; speedup vs baseline: 1.5796x; 1.5796x over previous
//
#include <hip/hip_runtime.h>
#include <stdint.h>

// Problem constants (fixed by the reference)
#define M_DIM 8192
#define K_DIM 4096
#define N_DIM 11008
#define KP_DIM 512     // K/8 packed int32 rows
// group size 128 along K -> group g = kp/16

// Workspace layout (bytes):
//   A_pre: M*K bf16 in fragment order  = 67,108,864
//   B_pre: K*N bf16 in fragment order  = 90,177,536
#define A_PRE_BYTES (67108864ull)
#define B_PRE_BYTES (90177536ull)
#define WS_NEEDED   (A_PRE_BYTES + B_PRE_BYTES)

typedef __attribute__((ext_vector_type(8))) short bf16x8;   // MFMA A/B frag (4 VGPRs)
typedef __attribute__((ext_vector_type(4))) float f32x4;    // MFMA C/D frag

// fp32 -> bf16 (round-to-nearest, ties up), packed pair
__device__ __forceinline__ uint32_t pack2_bf16(float lo, float hi) {
    uint32_t ulo = (__float_as_uint(lo) + 0x8000u) >> 16;
    uint32_t uhi = (__float_as_uint(hi) + 0x8000u) & 0xFFFF0000u;
    return uhi | ulo;
}

// One packed int32 (8 nibbles along K) -> 8 dequantized bf16 (one 16B frag chunk).
// 0x43000000|(nib<<16) is the fp32 bit pattern of (128+nib); w=(128+q)*s + b, b=-(128+z)*s.
__device__ __forceinline__ uint4 dequant_word(uint32_t w, float s, float b) {
    const uint32_t MG = 0x43000000u, MK = 0x000F0000u;
    float f0 = __uint_as_float(((w << 16) & MK) | MG);
    float f1 = __uint_as_float(((w << 12) & MK) | MG);
    float f2 = __uint_as_float(((w <<  8) & MK) | MG);
    float f3 = __uint_as_float(((w <<  4) & MK) | MG);
    float f4 = __uint_as_float(( w        & MK) | MG);
    float f5 = __uint_as_float(((w >>  4) & MK) | MG);
    float f6 = __uint_as_float(((w >>  8) & MK) | MG);
    float f7 = __uint_as_float(((w >> 12) & MK) | MG);
    uint4 o;
    o.x = pack2_bf16(fmaf(f0, s, b), fmaf(f1, s, b));
    o.y = pack2_bf16(fmaf(f2, s, b), fmaf(f3, s, b));
    o.z = pack2_bf16(fmaf(f4, s, b), fmaf(f5, s, b));
    o.w = pack2_bf16(fmaf(f6, s, b), fmaf(f7, s, b));
    return o;
}

// Fragment-order addressing (shared by prepasses and GEMM):
//   16B chunk index = ((blk128 * 64 + k_blk) * 16 + mt*2 + ks) * 64 + lane
//   lane = (q << 4) | (row_or_col & 15),  q = (k % 32) / 8,  ks = (k % 64) / 32
// GEMM stage (blk128, k_blk) is then 16 KB contiguous -> global_load_lds dwordx4
// with wave-uniform LDS base + lane*16, perfectly coalesced global reads.

// ---------------- Prepass 1: x fp32 -> A_pre bf16 fragment order ----------------
// grid (2, 8192) x 256: thread owns 8 consecutive k of one row (one 16B chunk)
__global__ void conv_x(const float* __restrict__ x, uint32_t* __restrict__ Apre) {
    const int c   = blockIdx.x * 256 + threadIdx.x;   // k-chunk 0..511
    const int row = blockIdx.y;
    const float4* p = reinterpret_cast<const float4*>(x + (size_t)row * K_DIM + c * 8);
    float4 v0 = p[0], v1 = p[1];
    uint4 o;
    o.x = pack2_bf16(v0.x, v0.y);
    o.y = pack2_bf16(v0.z, v0.w);
    o.z = pack2_bf16(v1.x, v1.y);
    o.w = pack2_bf16(v1.z, v1.w);
    const int m_blk = row >> 7, mt = (row >> 4) & 7, lrow = row & 15;
    const int k_blk = c >> 3, ks = (c >> 2) & 1, q = c & 3;
    const int lane  = (q << 4) | lrow;
    const size_t dst = (((size_t)m_blk * 64 + k_blk) * 16 + mt * 2 + ks) * 64 + lane;
    *reinterpret_cast<uint4*>(Apre + dst * 4) = o;
}

// ---------------- Prepass 2: W_q int4 -> B_pre bf16 fragment order ----------------
// grid (43, 512) x 256: thread owns one packed word (kp, n) = one 16B chunk
__global__ void dequant_w(const int* __restrict__ Wq, const float* __restrict__ scales,
                          const float* __restrict__ zeros, uint32_t* __restrict__ Bpre) {
    const int n  = blockIdx.x * 256 + threadIdx.x;   // 0..11007
    const int kp = blockIdx.y;                        // 0..511
    const uint32_t w = (uint32_t)Wq[(size_t)kp * N_DIM + n];
    const int g = kp >> 4;                            // k/128
    const float s = scales[(size_t)g * N_DIM + n];
    const float z = zeros[(size_t)g * N_DIM + n];
    const float b = -(128.0f + z) * s;
    uint4 o = dequant_word(w, s, b);
    const int n_blk = n >> 7, nt = (n >> 4) & 7;
    const int k_blk = kp >> 3, ks = (kp >> 2) & 1, q = kp & 3;
    const int lane  = (q << 4) | (n & 15);
    const size_t dst = (((size_t)n_blk * 64 + k_blk) * 16 + nt * 2 + ks) * 64 + lane;
    *reinterpret_cast<uint4*>(Bpre + dst * 4) = o;
}

// ---------------- Main GEMM: pure bf16, m97 pattern ----------------
#define GLD16(g, l) __builtin_amdgcn_global_load_lds(                        \
    (const __attribute__((address_space(1))) uint32_t*)(g),                  \
    (__attribute__((address_space(3))) uint32_t*)(l), 16, 0, 0)

__global__ __launch_bounds__(256, 2)
void gemm_pre(const uint32_t* __restrict__ Apre, const uint32_t* __restrict__ Bpre,
              float* __restrict__ out) {
    __shared__ uint32_t As[4096];   // 16 KB, fragment order: 16 blocks of 1 KB
    __shared__ uint32_t Bs[4096];

    const int tid  = threadIdx.x;
    const int lane = tid & 63;
    const int wv   = tid >> 6;
    const int wm   = wv >> 1, wn = wv & 1;
    const int m_blk = blockIdx.x, n_blk = blockIdx.y;

    // wave wv stages A-blocks and B-blocks wv*4 .. wv*4+3 each stage
    const uint32_t* ag = Apre + ((size_t)m_blk * 64 * 16 + wv * 4) * 256 + lane * 4;
    const uint32_t* bg = Bpre + ((size_t)n_blk * 64 * 16 + wv * 4) * 256 + lane * 4;
    uint32_t* al = &As[(wv * 4) * 256];   // wave-uniform LDS bases
    uint32_t* bl = &Bs[(wv * 4) * 256];

    f32x4 acc[4][4];
#pragma unroll
    for (int mt = 0; mt < 4; ++mt)
#pragma unroll
        for (int nt = 0; nt < 4; ++nt)
            acc[mt][nt] = (f32x4){0.f, 0.f, 0.f, 0.f};

    for (int kb = 0; kb < 64; ++kb) {
#pragma unroll
        for (int i = 0; i < 4; ++i) {
            GLD16(ag + i * 256, al + i * 256);
            GLD16(bg + i * 256, bl + i * 256);
        }
        ag += 4096;   // next 16 KB stage
        bg += 4096;
        __syncthreads();

#pragma unroll
        for (int ks = 0; ks < 2; ++ks) {
            bf16x8 af[4], bfr[4];
#pragma unroll
            for (int mt = 0; mt < 4; ++mt)
                af[mt] = *reinterpret_cast<const bf16x8*>(
                    &As[(((wm * 4 + mt) << 1) | ks) * 256 + lane * 4]);
#pragma unroll
            for (int nt = 0; nt < 4; ++nt)
                bfr[nt] = *reinterpret_cast<const bf16x8*>(
                    &Bs[(((wn * 4 + nt) << 1) | ks) * 256 + lane * 4]);
#pragma unroll
            for (int mt = 0; mt < 4; ++mt)
#pragma unroll
                for (int nt = 0; nt < 4; ++nt)
                    acc[mt][nt] = __builtin_amdgcn_mfma_f32_16x16x32_bf16(
                        af[mt], bfr[nt], acc[mt][nt], 0, 0, 0);
        }
        __syncthreads();
    }

    // epilogue: C/D layout col = lane&15, row = (lane>>4)*4 + reg  [m89/m91]
    const int colc = lane & 15, qr = lane >> 4;
#pragma unroll
    for (int mt = 0; mt < 4; ++mt) {
#pragma unroll
        for (int nt = 0; nt < 4; ++nt) {
            int row0 = m_blk * 128 + (wm * 4 + mt) * 16 + qr * 4;
            int c    = n_blk * 128 + (wn * 4 + nt) * 16 + colc;
#pragma unroll
            for (int i = 0; i < 4; ++i)
                out[(size_t)(row0 + i) * N_DIM + c] = acc[mt][nt][i];
        }
    }
}

// ---------------- Fallback: round-1 fused kernel (used only if ws too small) ----------------
__global__ __launch_bounds__(256, 2)
void qgemm_fused(const float* __restrict__ x, const int* __restrict__ Wq,
                 const float* __restrict__ scales, const float* __restrict__ zeros,
                 float* __restrict__ out) {
    __shared__ uint32_t As[4096];
    __shared__ uint32_t Bs[4096];

    const int tid  = threadIdx.x;
    const int lane = tid & 63;
    const int wv   = tid >> 6;
    const int wm   = wv >> 1, wn = wv & 1;
    const int m0 = blockIdx.x * 128;
    const int n0 = blockIdx.y * 128;
    const int bc  = tid & 127;
    const int brh = tid >> 7;

    int a_row[4], a_col[4], a_dst[4];
#pragma unroll
    for (int j = 0; j < 4; ++j) {
        int sl  = tid + 256 * j;
        int blk = sl >> 6;
        int ln  = sl & 63;
        int mt  = blk >> 1, ks = blk & 1;
        a_row[j] = m0 + mt * 16 + (ln & 15);
        a_col[j] = ks * 32 + (ln >> 4) * 8;
        a_dst[j] = blk * 256 + ln * 4;
    }

    f32x4 acc[4][4];
#pragma unroll
    for (int mt = 0; mt < 4; ++mt)
#pragma unroll
        for (int nt = 0; nt < 4; ++nt)
            acc[mt][nt] = (f32x4){0.f, 0.f, 0.f, 0.f};

    float4   pa[4][2];
    uint32_t pw[4];
    float    s_raw, z_raw;
#pragma unroll
    for (int j = 0; j < 4; ++j) {
        const float4* p = reinterpret_cast<const float4*>(
            x + (size_t)a_row[j] * K_DIM + a_col[j]);
        pa[j][0] = p[0];
        pa[j][1] = p[1];
    }
#pragma unroll
    for (int j = 0; j < 4; ++j) {
        int r = brh * 4 + j;
        pw[j] = (uint32_t)Wq[(size_t)r * N_DIM + n0 + bc];
    }
    s_raw = scales[n0 + bc];
    z_raw = zeros[n0 + bc];

    float sv = 0.f, bv = 0.f;

    for (int kk = 0; kk < K_DIM; kk += 64) {
        if ((kk & 127) == 0) {
            sv = s_raw;
            bv = -(128.0f + z_raw) * s_raw;
        }
#pragma unroll
        for (int j = 0; j < 4; ++j) {
            uint4 o;
            o.x = pack2_bf16(pa[j][0].x, pa[j][0].y);
            o.y = pack2_bf16(pa[j][0].z, pa[j][0].w);
            o.z = pack2_bf16(pa[j][1].x, pa[j][1].y);
            o.w = pack2_bf16(pa[j][1].z, pa[j][1].w);
            *reinterpret_cast<uint4*>(&As[a_dst[j]]) = o;
        }
#pragma unroll
        for (int j = 0; j < 4; ++j) {
            int r  = brh * 4 + j;
            uint4 o = dequant_word(pw[j], sv, bv);
            int ks  = r >> 2, q = r & 3;
            int blk = ((bc >> 4) << 1) | ks;
            *reinterpret_cast<uint4*>(&Bs[blk * 256 + (q * 16 + (bc & 15)) * 4]) = o;
        }
        __syncthreads();

        int kn = kk + 64;
        if (kn < K_DIM) {
#pragma unroll
            for (int j = 0; j < 4; ++j) {
                const float4* p = reinterpret_cast<const float4*>(
                    x + (size_t)a_row[j] * K_DIM + kn + a_col[j]);
                pa[j][0] = p[0];
                pa[j][1] = p[1];
            }
            int kp0 = kn >> 3;
#pragma unroll
            for (int j = 0; j < 4; ++j) {
                int r = brh * 4 + j;
                pw[j] = (uint32_t)Wq[(size_t)(kp0 + r) * N_DIM + n0 + bc];
            }
            if ((kn & 127) == 0) {
                int g = kn >> 7;
                s_raw = scales[(size_t)g * N_DIM + n0 + bc];
                z_raw = zeros[(size_t)g * N_DIM + n0 + bc];
            }
        }

#pragma unroll
        for (int ks = 0; ks < 2; ++ks) {
            bf16x8 af[4], bfr[4];
#pragma unroll
            for (int mt = 0; mt < 4; ++mt)
                af[mt] = *reinterpret_cast<const bf16x8*>(
                    &As[(((wm * 4 + mt) << 1) | ks) * 256 + lane * 4]);
#pragma unroll
            for (int nt = 0; nt < 4; ++nt)
                bfr[nt] = *reinterpret_cast<const bf16x8*>(
                    &Bs[(((wn * 4 + nt) << 1) | ks) * 256 + lane * 4]);
#pragma unroll
            for (int mt = 0; mt < 4; ++mt)
#pragma unroll
                for (int nt = 0; nt < 4; ++nt)
                    acc[mt][nt] = __builtin_amdgcn_mfma_f32_16x16x32_bf16(
                        af[mt], bfr[nt], acc[mt][nt], 0, 0, 0);
        }
        __syncthreads();
    }

    const int colc = lane & 15, qr = lane >> 4;
#pragma unroll
    for (int mt = 0; mt < 4; ++mt) {
#pragma unroll
        for (int nt = 0; nt < 4; ++nt) {
            int row0 = m0 + (wm * 4 + mt) * 16 + qr * 4;
            int c    = n0 + (wn * 4 + nt) * 16 + colc;
#pragma unroll
            for (int i = 0; i < 4; ++i)
                out[(size_t)(row0 + i) * N_DIM + c] = acc[mt][nt][i];
        }
    }
}

extern "C" void kernel_launch(void* const* d_in, const int* in_sizes, int n_in,
                              void* d_out, int out_size, void* d_ws, size_t ws_size,
                              hipStream_t stream) {
    const float* x      = (const float*)d_in[0];
    const int*   Wq     = (const int*)d_in[1];
    const float* scales = (const float*)d_in[2];
    const float* zeros  = (const float*)d_in[3];
    float*       out    = (float*)d_out;

    if (ws_size >= WS_NEEDED) {
        uint32_t* Apre = (uint32_t*)d_ws;
        uint32_t* Bpre = (uint32_t*)((char*)d_ws + A_PRE_BYTES);
        conv_x<<<dim3(2, M_DIM), dim3(256), 0, stream>>>(x, Apre);
        dequant_w<<<dim3(N_DIM / 256, KP_DIM), dim3(256), 0, stream>>>(Wq, scales, zeros, Bpre);
        gemm_pre<<<dim3(M_DIM / 128, N_DIM / 128), dim3(256), 0, stream>>>(Apre, Bpre, out);
    } else {
        qgemm_fused<<<dim3(M_DIM / 128, N_DIM / 128), dim3(256), 0, stream>>>(
            x, Wq, scales, zeros, out);
    }
}